// Round 6
// baseline (106.672 us; speedup 1.0000x reference)
//
#include <hip/hip_runtime.h>
#include <math.h>

// (B,C,H,W) = (16,256,80,80), GROUPS=32 -> 512 group-instances of 8x80x80
constexpr int CG  = 8;
constexpr int HW  = 6400;          // 80*80
constexpr int NG  = 512;           // B*GROUPS
constexpr int TSF = 88;            // LDS tile row stride (floats): b128 rows 4-way
constexpr float EPSf = 1e-5f;

__device__ __forceinline__ float sigmoidf(float v) {
    return 1.0f / (1.0f + __expf(-v));
}

// One block per group. 1024 threads (16 waves), 2 blocks/CU (LDS ~77.7 KB,
// VGPR capped at 64 via launch bounds) -> 32 waves/CU: barrier stalls of one
// block hide under the other. x read once cold (phase A, double-buffered
// channel tiles), re-read twice from L2/L3 (stats, output) - R2 counters
// showed those re-reads are cache-absorbed (FETCH 151 MB vs 105 ideal).
__global__ __launch_bounds__(1024, 8) void k_fused(
    const float* __restrict__ x,
    const float* __restrict__ conv_w,
    const float* __restrict__ conv_b,
    const float* __restrict__ gnw,
    const float* __restrict__ gnb,
    float* __restrict__ out)
{
    const int bg  = blockIdx.x;            // 0..511
    const int tid = threadIdx.x;           // 0..1023

    __shared__ float tl[2][80 * TSF];      // double-buffered channel tile
    __shared__ float pools[4 * 640];       // [a][c][p]: a0=mh a1=mw a2=xh a3=xw
    __shared__ float g[4 * 640];           // gates (h-gates coef-folded later)
    __shared__ float wsm[64];
    __shared__ float cbs[8];
    __shared__ float red[16][6];
    __shared__ float Axs[8], Bxs[8], Ays[8], Bys[8], ymaxs[8], cHx[8], cHy[8];
    __shared__ float kcs;

    if (tid < 64) wsm[tid] = conv_w[tid];
    if (tid < 8)  cbs[tid] = conv_b[tid];

    const float* base = x + (size_t)bg * CG * HW;

    // ---------------- Phase A: pools over 8 channels, double-buffered ------
    // prologue: stage channel 0 into tl[0]
    {
        const float4 p0 = ((const float4*)base)[tid];              // tid<1600
        float4 p1;
        if (tid < 576) p1 = ((const float4*)base)[1024 + tid];
        *(float4*)&tl[0][(tid / 20) * TSF + (tid % 20) * 4] = p0;
        if (tid < 576) {
            const int v = 1024 + tid;
            *(float4*)&tl[0][(v / 20) * TSF + (v % 20) * 4] = p1;
        }
    }
    __syncthreads();

    for (int c = 0; c < 8; ++c) {
        const int cur = c & 1;
        float4 p0, p1;
        if (c < 7) {                       // issue prefetch of channel c+1
            const float* cb = base + (c + 1) * HW;
            p0 = ((const float4*)cb)[tid];
            if (tid < 576) p1 = ((const float4*)cb)[1024 + tid];
        }
        // rows: threads 0..319 (4 per row); cols: threads 512..831 (4 per col)
        if (tid < 320) {
            const int r = tid >> 2, q = tid & 3;
            const float4* rp = (const float4*)&tl[cur][r * TSF];
            float s = 0.f, m = -INFINITY;
            #pragma unroll
            for (int k = q * 5; k < q * 5 + 5; ++k) {
                float4 d = rp[k];
                s += (d.x + d.y) + (d.z + d.w);
                m = fmaxf(m, fmaxf(fmaxf(d.x, d.y), fmaxf(d.z, d.w)));
            }
            s += __shfl_down(s, 2, 4); s += __shfl_down(s, 1, 4);
            m = fmaxf(m, __shfl_down(m, 2, 4));
            m = fmaxf(m, __shfl_down(m, 1, 4));
            if (q == 0) {
                pools[0 * 640 + c * 80 + r] = s * (1.f / 80.f);
                pools[2 * 640 + c * 80 + r] = m;
            }
        } else if (tid >= 512 && tid < 832) {
            const int e = tid - 512, j = e >> 2, q = e & 3;
            float s = 0.f, m = -INFINITY;
            #pragma unroll 5
            for (int hh = q * 20; hh < q * 20 + 20; ++hh) {
                const float vv = tl[cur][hh * TSF + j];
                s += vv;
                m = fmaxf(m, vv);
            }
            s += __shfl_down(s, 2, 4); s += __shfl_down(s, 1, 4);
            m = fmaxf(m, __shfl_down(m, 2, 4));
            m = fmaxf(m, __shfl_down(m, 1, 4));
            if (q == 0) {
                pools[1 * 640 + c * 80 + j] = s * (1.f / 80.f);
                pools[3 * 640 + c * 80 + j] = m;
            }
        }
        if (c < 7) {                       // stage prefetched channel
            float* nx = tl[cur ^ 1];
            *(float4*)&nx[(tid / 20) * TSF + (tid % 20) * 4] = p0;
            if (tid < 576) {
                const int v = 1024 + tid;
                *(float4*)&nx[(v / 20) * TSF + (v % 20) * 4] = p1;
            }
        }
        __syncthreads();
    }

    // ---------------- Phase B: gates = sigmoid(8x8 conv of pools) ----------
    #pragma unroll
    for (int i = 0; i < 3; ++i) {
        const int e = tid + i * 1024;
        if (e < 2560) {
            const int a = e / 640, rem = e % 640, c = rem / 80, p = rem % 80;
            float acc = cbs[c];
            #pragma unroll
            for (int cc = 0; cc < 8; ++cc)
                acc += wsm[c * 8 + cc] * pools[a * 640 + cc * 80 + p];
            g[e] = sigmoidf(acc);
        }
    }
    __syncthreads();

    // ------- Phase C: per-channel gated stats (128 thr/ch, L2/L3 re-read) --
    {
        const int c = tid >> 7, sl = tid & 127;
        const float* cb_ = base + c * HW;
        float s1x = 0.f, s2x = 0.f, s1y = 0.f, s2y = 0.f;
        float my = -INFINITY, ny = INFINITY;
        #pragma unroll 4
        for (int j = 0; j < 13; ++j) {
            const int v = sl + j * 128;
            if (v < 1600) {
                float4 d = ((const float4*)cb_)[v];
                const int h = v / 20, w0 = (v % 20) * 4;
                const float ghx = g[0 * 640 + c * 80 + h];
                const float ghy = g[2 * 640 + c * 80 + h];
                const float4 gwx = *(const float4*)&g[1 * 640 + c * 80 + w0];
                const float4 gwy = *(const float4*)&g[3 * 640 + c * 80 + w0];
                const float dd[4]  = {d.x, d.y, d.z, d.w};
                const float gx4[4] = {gwx.x, gwx.y, gwx.z, gwx.w};
                const float gy4[4] = {gwy.x, gwy.y, gwy.z, gwy.w};
                #pragma unroll
                for (int k = 0; k < 4; ++k) {
                    const float tx = dd[k] * ghx * gx4[k];
                    const float ty = dd[k] * ghy * gy4[k];
                    s1x += tx; s2x += tx * tx;
                    s1y += ty; s2y += ty * ty;
                    my = fmaxf(my, ty); ny = fminf(ny, ty);
                }
            }
        }
        #pragma unroll
        for (int off = 32; off > 0; off >>= 1) {
            s1x += __shfl_down(s1x, off);
            s2x += __shfl_down(s2x, off);
            s1y += __shfl_down(s1y, off);
            s2y += __shfl_down(s2y, off);
            my = fmaxf(my, __shfl_down(my, off));
            ny = fminf(ny, __shfl_down(ny, off));
        }
        const int wv = tid >> 6;
        if ((tid & 63) == 0) {
            red[wv][0] = s1x; red[wv][1] = s2x; red[wv][2] = s1y;
            red[wv][3] = s2y; red[wv][4] = my;  red[wv][5] = ny;
        }
    }
    __syncthreads();

    // ---------------- Phase D: finalize + softmaxes + fold -----------------
    if (tid < 8) {
        const float s1x = red[2 * tid][0] + red[2 * tid + 1][0];
        const float s2x = red[2 * tid][1] + red[2 * tid + 1][1];
        const float s1y = red[2 * tid][2] + red[2 * tid + 1][2];
        const float s2y = red[2 * tid][3] + red[2 * tid + 1][3];
        const float my  = fmaxf(red[2 * tid][4], red[2 * tid + 1][4]);
        const float ny  = fminf(red[2 * tid][5], red[2 * tid + 1][5]);
        const float w = gnw[tid], b = gnb[tid];
        const float mux  = s1x * (1.f / 6400.f);
        const float varx = s2x * (1.f / 6400.f) - mux * mux;
        const float ax   = rsqrtf(varx + EPSf) * w;
        Axs[tid] = ax; Bxs[tid] = b - mux * ax;
        const float muy  = s1y * (1.f / 6400.f);
        const float vary = s2y * (1.f / 6400.f) - muy * muy;
        const float ay   = rsqrtf(vary + EPSf) * w;
        Ays[tid] = ay; Bys[tid] = b - muy * ay;
        ymaxs[tid] = (ay >= 0.f ? my : ny) * ay + Bys[tid];
    }
    __syncthreads();
    if (tid == 0) {
        // x12 = softmax(gn_b): HW-mean of an HW-normalized tensor is gn_b.
        float x12[8], y12[8];
        float mb = -INFINITY;
        for (int c = 0; c < 8; ++c) mb = fmaxf(mb, gnb[c]);
        float se = 0.f;
        for (int c = 0; c < 8; ++c) { x12[c] = __expf(gnb[c] - mb); se += x12[c]; }
        float inv = 1.f / se;
        for (int c = 0; c < 8; ++c) x12[c] *= inv;
        float m2 = -INFINITY;
        for (int c = 0; c < 8; ++c) m2 = fmaxf(m2, ymaxs[c]);
        se = 0.f;
        for (int c = 0; c < 8; ++c) { y12[c] = __expf(ymaxs[c] - m2); se += y12[c]; }
        inv = 1.f / se;
        float kc = 0.f;
        for (int c = 0; c < 8; ++c) {
            y12[c] *= inv;
            cHx[c] = y12[c] * Axs[c];   // scales mean-branch h-gate
            cHy[c] = x12[c] * Ays[c];   // scales max-branch  h-gate
            kc += x12[c] * Bys[c] + y12[c] * Bxs[c];
        }
        kcs = kc;
    }
    __syncthreads();
    if (tid < 640) {
        g[tid]        *= cHx[tid / 80];          // a=0 (mean-branch h)
        g[1280 + tid] *= cHy[tid / 80];          // a=2 (max-branch h)
    }
    __syncthreads();

    // ---------------- Phase E: weights -> sigmoid -> output ----------------
    const float kc = kcs;
    float* ob = out + (size_t)bg * CG * HW;
    #pragma unroll
    for (int i = 0; i < 2; ++i) {
        const int v = tid + i * 1024;
        if (v < 1600) {
            const int h = v / 20, w0 = (v % 20) * 4;
            float4 gxv[8];
            #pragma unroll
            for (int c = 0; c < 8; ++c)
                gxv[c] = *(const float4*)(base + c * HW + v * 4);

            float s0 = kc, s1 = kc, s2 = kc, s3 = kc;
            #pragma unroll
            for (int c = 0; c < 8; ++c) {
                const float chx = g[0 * 640 + c * 80 + h];
                const float chy = g[1280 + c * 80 + h];
                const float4 cwx = *(const float4*)&g[640  + c * 80 + w0];
                const float4 cwy = *(const float4*)&g[1920 + c * 80 + w0];
                s0 += gxv[c].x * (chy * cwy.x + chx * cwx.x);
                s1 += gxv[c].y * (chy * cwy.y + chx * cwx.y);
                s2 += gxv[c].z * (chy * cwy.z + chx * cwx.z);
                s3 += gxv[c].w * (chy * cwy.w + chx * cwx.w);
            }
            s0 = sigmoidf(s0); s1 = sigmoidf(s1);
            s2 = sigmoidf(s2); s3 = sigmoidf(s3);
            #pragma unroll
            for (int c = 0; c < 8; ++c) {
                float4 o;
                o.x = gxv[c].x * s0; o.y = gxv[c].y * s1;
                o.z = gxv[c].z * s2; o.w = gxv[c].w * s3;
                *(float4*)(ob + c * HW + v * 4) = o;
            }
        }
    }
}

extern "C" void kernel_launch(void* const* d_in, const int* in_sizes, int n_in,
                              void* d_out, int out_size, void* d_ws, size_t ws_size,
                              hipStream_t stream) {
    const float* x      = (const float*)d_in[0];
    const float* conv_w = (const float*)d_in[1];
    const float* conv_b = (const float*)d_in[2];
    const float* gn_w   = (const float*)d_in[3];
    const float* gn_b   = (const float*)d_in[4];
    float* out = (float*)d_out;
    (void)d_ws; (void)ws_size;

    k_fused<<<NG, 1024, 0, stream>>>(x, conv_w, conv_b, gn_w, gn_b, out);
}

// Round 7
// 96.775 us; speedup vs baseline: 1.1023x; 1.1023x over previous
//
#include <hip/hip_runtime.h>
#include <math.h>

// (B,C,H,W) = (16,256,80,80), GROUPS=32 -> 512 group-instances of 8x80x80
constexpr int CG   = 8;
constexpr int Hh   = 80;
constexpr int HW   = 6400;         // 80*80
constexpr int NG   = 512;          // B*GROUPS
constexpr int NCH  = NG * CG;      // 4096 channels
constexpr int PP   = NCH * 80;     // 327680 floats per pool array
constexpr float EPSf = 1e-5f;
// ws: pools only, [a*PP + bgc*80 + p], a = 0:mean_h 1:mean_w 2:max_h 3:max_w

__device__ __forceinline__ float sigmoidf(float v) {
    return 1.0f / (1.0f + __expf(-v));
}

// ---------------- K1: per-channel row/col mean+max pools (cold HBM) --------
__global__ __launch_bounds__(256) void k_pool(const float* __restrict__ x,
                                              float* __restrict__ ws) {
    const int bgc = blockIdx.x;                 // 0..4095
    const float* base = x + (size_t)bgc * HW;
    __shared__ float tile[Hh * 84];             // pad stride 84

    for (int v = threadIdx.x; v < 1600; v += 256) {
        int h  = v / 20;
        int w0 = (v % 20) * 4;
        float4 d = ((const float4*)base)[v];
        *(float4*)&tile[h * 84 + w0] = d;
    }
    __syncthreads();

    const int t = threadIdx.x;
    if (t < 80) {
        // row t: mean/max over w  (waves 0-1)
        float s = 0.f, m = -INFINITY;
        const float4* r = (const float4*)&tile[t * 84];
        #pragma unroll
        for (int i = 0; i < 20; i++) {
            float4 d = r[i];
            s += d.x + d.y + d.z + d.w;
            m = fmaxf(m, fmaxf(fmaxf(d.x, d.y), fmaxf(d.z, d.w)));
        }
        ws[0 * PP + bgc * 80 + t] = s * (1.f / 80.f);
        ws[2 * PP + bgc * 80 + t] = m;
    } else if (t >= 128 && t < 208) {
        // col (t-128): mean/max over h  (waves 2-3)
        const int c = t - 128;
        float s2 = 0.f, m2 = -INFINITY;
        #pragma unroll 8
        for (int i = 0; i < 80; i++) {
            float v = tile[i * 84 + c];
            s2 += v;
            m2 = fmaxf(m2, v);
        }
        ws[1 * PP + bgc * 80 + c] = s2 * (1.f / 80.f);
        ws[3 * PP + bgc * 80 + c] = m2;
    }
}

// ------- K2: gates + stats + finalize + output, x register-resident --------
// One block per group, 1024 threads. Thread t owns spatial float4 slot t
// (and t+1024 if t<576) ACROSS ALL 8 CHANNELS: 8-16 float4 in registers.
// Channel sums for both stats and the output weights are thread-local; x is
// read exactly once here (L3-hot after k_pool), no spill (VGPR<=128).
__global__ __launch_bounds__(1024, 4) void k_rest(
    const float* __restrict__ x,
    const float* __restrict__ conv_w,
    const float* __restrict__ conv_b,
    const float* __restrict__ gnw,
    const float* __restrict__ gnb,
    const float* __restrict__ ws,
    float* __restrict__ out)
{
    const int bg  = blockIdx.x;            // 0..511
    const int tid = threadIdx.x;           // 0..1023

    __shared__ float pl[2560];             // pools [a][c][p]
    __shared__ float g[2560];              // gates  [a][c][p]
    __shared__ float wsm[64];
    __shared__ float cbs[8];
    __shared__ float red[16][8][6];
    __shared__ float Axs[8], Bxs[8], Ays[8], Bys[8], ymaxs[8], cHx[8], cHy[8];
    __shared__ float kcs;

    if (tid < 64) wsm[tid] = conv_w[tid];
    if (tid < 8)  cbs[tid] = conv_b[tid];
    #pragma unroll
    for (int i = 0; i < 3; ++i) {
        const int e = tid + i * 1024;
        if (e < 2560) {
            const int a = e / 640, rem = e % 640, c = rem / 80, p = rem % 80;
            pl[e] = ws[a * PP + (bg * 8 + c) * 80 + p];
        }
    }

    // x -> registers (issued early; latency hides under gate conv)
    const float* base = x + (size_t)bg * CG * HW;
    const int s0 = tid, s1 = tid + 1024;           // spatial f4 slots
    float4 xr0[8], xr1[8];
    #pragma unroll
    for (int c = 0; c < 8; ++c) xr0[c] = ((const float4*)(base + c * HW))[s0];
    if (tid < 576) {                               // wave-aligned (9 waves)
        #pragma unroll
        for (int c = 0; c < 8; ++c) xr1[c] = ((const float4*)(base + c * HW))[s1];
    }
    __syncthreads();                               // pl ready

    // gates = sigmoid(8x8 conv of pools)
    #pragma unroll
    for (int i = 0; i < 3; ++i) {
        const int e = tid + i * 1024;
        if (e < 2560) {
            const int a = e / 640, rem = e % 640, c = rem / 80, p = rem % 80;
            float acc = cbs[c];
            #pragma unroll
            for (int cc = 0; cc < 8; ++cc)
                acc += wsm[c * 8 + cc] * pl[a * 640 + cc * 80 + p];
            g[e] = sigmoidf(acc);
        }
    }
    __syncthreads();                               // g ready

    // per-channel gated stats from registers
    const int h0 = s0 / 20, w00 = (s0 % 20) * 4;
    const int h1 = s1 / 20, w01 = (s1 % 20) * 4;
    const int wv = tid >> 6, lane = tid & 63;
    #pragma unroll
    for (int c = 0; c < 8; ++c) {
        float s1x = 0.f, s2x = 0.f, s1y = 0.f, s2y = 0.f;
        float my = -INFINITY, ny = INFINITY;
        {
            const float ghx = g[c * 80 + h0],  ghy = g[1280 + c * 80 + h0];
            const float4 gwx = *(const float4*)&g[640  + c * 80 + w00];
            const float4 gwy = *(const float4*)&g[1920 + c * 80 + w00];
            const float dd[4]  = {xr0[c].x, xr0[c].y, xr0[c].z, xr0[c].w};
            const float gx4[4] = {gwx.x, gwx.y, gwx.z, gwx.w};
            const float gy4[4] = {gwy.x, gwy.y, gwy.z, gwy.w};
            #pragma unroll
            for (int k = 0; k < 4; ++k) {
                const float tx = dd[k] * ghx * gx4[k];
                const float ty = dd[k] * ghy * gy4[k];
                s1x += tx; s2x += tx * tx;
                s1y += ty; s2y += ty * ty;
                my = fmaxf(my, ty); ny = fminf(ny, ty);
            }
        }
        if (tid < 576) {
            const float ghx = g[c * 80 + h1],  ghy = g[1280 + c * 80 + h1];
            const float4 gwx = *(const float4*)&g[640  + c * 80 + w01];
            const float4 gwy = *(const float4*)&g[1920 + c * 80 + w01];
            const float dd[4]  = {xr1[c].x, xr1[c].y, xr1[c].z, xr1[c].w};
            const float gx4[4] = {gwx.x, gwx.y, gwx.z, gwx.w};
            const float gy4[4] = {gwy.x, gwy.y, gwy.z, gwy.w};
            #pragma unroll
            for (int k = 0; k < 4; ++k) {
                const float tx = dd[k] * ghx * gx4[k];
                const float ty = dd[k] * ghy * gy4[k];
                s1x += tx; s2x += tx * tx;
                s1y += ty; s2y += ty * ty;
                my = fmaxf(my, ty); ny = fminf(ny, ty);
            }
        }
        #pragma unroll
        for (int off = 32; off > 0; off >>= 1) {
            s1x += __shfl_down(s1x, off);
            s2x += __shfl_down(s2x, off);
            s1y += __shfl_down(s1y, off);
            s2y += __shfl_down(s2y, off);
            my = fmaxf(my, __shfl_down(my, off));
            ny = fminf(ny, __shfl_down(ny, off));
        }
        if (lane == 0) {
            red[wv][c][0] = s1x; red[wv][c][1] = s2x; red[wv][c][2] = s1y;
            red[wv][c][3] = s2y; red[wv][c][4] = my;  red[wv][c][5] = ny;
        }
    }
    __syncthreads();

    // finalize affine-norm constants
    if (tid < 8) {
        float a0 = 0.f, a1 = 0.f, a2 = 0.f, a3 = 0.f;
        float a4 = -INFINITY, a5 = INFINITY;
        #pragma unroll
        for (int w2 = 0; w2 < 16; ++w2) {
            a0 += red[w2][tid][0]; a1 += red[w2][tid][1];
            a2 += red[w2][tid][2]; a3 += red[w2][tid][3];
            a4 = fmaxf(a4, red[w2][tid][4]);
            a5 = fminf(a5, red[w2][tid][5]);
        }
        const float w = gnw[tid], b = gnb[tid];
        const float mux  = a0 * (1.f / 6400.f);
        const float varx = a1 * (1.f / 6400.f) - mux * mux;
        const float ax   = rsqrtf(varx + EPSf) * w;
        Axs[tid] = ax; Bxs[tid] = b - mux * ax;
        const float muy  = a2 * (1.f / 6400.f);
        const float vary = a3 * (1.f / 6400.f) - muy * muy;
        const float ay   = rsqrtf(vary + EPSf) * w;
        Ays[tid] = ay; Bys[tid] = b - muy * ay;
        ymaxs[tid] = (ay >= 0.f ? a4 : a5) * ay + Bys[tid];
    }
    __syncthreads();
    if (tid == 0) {
        // x12 = softmax(gn_b): HW-mean of an HW-normalized tensor is gn_b.
        float x12[8], y12[8];
        float mb = -INFINITY;
        for (int c = 0; c < 8; ++c) mb = fmaxf(mb, gnb[c]);
        float se = 0.f;
        for (int c = 0; c < 8; ++c) { x12[c] = __expf(gnb[c] - mb); se += x12[c]; }
        float inv = 1.f / se;
        for (int c = 0; c < 8; ++c) x12[c] *= inv;
        float m2 = -INFINITY;
        for (int c = 0; c < 8; ++c) m2 = fmaxf(m2, ymaxs[c]);
        se = 0.f;
        for (int c = 0; c < 8; ++c) { y12[c] = __expf(ymaxs[c] - m2); se += y12[c]; }
        inv = 1.f / se;
        float kc = 0.f;
        for (int c = 0; c < 8; ++c) {
            y12[c] *= inv;
            cHx[c] = y12[c] * Axs[c];   // scales mean-branch h-gate
            cHy[c] = x12[c] * Ays[c];   // scales max-branch  h-gate
            kc += x12[c] * Bys[c] + y12[c] * Bxs[c];
        }
        kcs = kc;
    }
    __syncthreads();
    if (tid < 640) {
        g[tid]        *= cHx[tid / 80];          // a=0 (mean-branch h)
        g[1280 + tid] *= cHy[tid / 80];          // a=2 (max-branch h)
    }
    __syncthreads();

    // output from registers
    const float kc = kcs;
    float* ob = out + (size_t)bg * CG * HW;
    {
        float u0 = kc, u1 = kc, u2 = kc, u3 = kc;
        #pragma unroll
        for (int c = 0; c < 8; ++c) {
            const float chx = g[c * 80 + h0], chy = g[1280 + c * 80 + h0];
            const float4 cwx = *(const float4*)&g[640  + c * 80 + w00];
            const float4 cwy = *(const float4*)&g[1920 + c * 80 + w00];
            u0 += xr0[c].x * (chy * cwy.x + chx * cwx.x);
            u1 += xr0[c].y * (chy * cwy.y + chx * cwx.y);
            u2 += xr0[c].z * (chy * cwy.z + chx * cwx.z);
            u3 += xr0[c].w * (chy * cwy.w + chx * cwx.w);
        }
        u0 = sigmoidf(u0); u1 = sigmoidf(u1);
        u2 = sigmoidf(u2); u3 = sigmoidf(u3);
        #pragma unroll
        for (int c = 0; c < 8; ++c) {
            float4 o;
            o.x = xr0[c].x * u0; o.y = xr0[c].y * u1;
            o.z = xr0[c].z * u2; o.w = xr0[c].w * u3;
            ((float4*)(ob + c * HW))[s0] = o;
        }
    }
    if (tid < 576) {
        float u0 = kc, u1 = kc, u2 = kc, u3 = kc;
        #pragma unroll
        for (int c = 0; c < 8; ++c) {
            const float chx = g[c * 80 + h1], chy = g[1280 + c * 80 + h1];
            const float4 cwx = *(const float4*)&g[640  + c * 80 + w01];
            const float4 cwy = *(const float4*)&g[1920 + c * 80 + w01];
            u0 += xr1[c].x * (chy * cwy.x + chx * cwx.x);
            u1 += xr1[c].y * (chy * cwy.y + chx * cwx.y);
            u2 += xr1[c].z * (chy * cwy.z + chx * cwx.z);
            u3 += xr1[c].w * (chy * cwy.w + chx * cwx.w);
        }
        u0 = sigmoidf(u0); u1 = sigmoidf(u1);
        u2 = sigmoidf(u2); u3 = sigmoidf(u3);
        #pragma unroll
        for (int c = 0; c < 8; ++c) {
            float4 o;
            o.x = xr1[c].x * u0; o.y = xr1[c].y * u1;
            o.z = xr1[c].z * u2; o.w = xr1[c].w * u3;
            ((float4*)(ob + c * HW))[s1] = o;
        }
    }
}

extern "C" void kernel_launch(void* const* d_in, const int* in_sizes, int n_in,
                              void* d_out, int out_size, void* d_ws, size_t ws_size,
                              hipStream_t stream) {
    const float* x      = (const float*)d_in[0];
    const float* conv_w = (const float*)d_in[1];
    const float* conv_b = (const float*)d_in[2];
    const float* gn_w   = (const float*)d_in[3];
    const float* gn_b   = (const float*)d_in[4];
    float* out = (float*)d_out;
    float* ws  = (float*)d_ws;   // 4*PP floats ~ 5.2 MB

    k_pool<<<NCH, 256, 0, stream>>>(x, ws);
    k_rest<<<NG, 1024, 0, stream>>>(x, conv_w, conv_b, gn_w, gn_b, ws, out);
}

// Round 8
// 72.579 us; speedup vs baseline: 1.4697x; 1.3334x over previous
//
#include <hip/hip_runtime.h>
#include <math.h>

// (B,C,H,W) = (16,256,80,80), GROUPS=32 -> 512 group-instances of 8x80x80
constexpr int CG   = 8;
constexpr int Hh   = 80;
constexpr int HW   = 6400;         // 80*80
constexpr int NG   = 512;          // B*GROUPS
constexpr int NCH  = NG * CG;      // 4096 channels
constexpr int PP   = NCH * 80;     // 327680 floats per pool array
constexpr float EPSf = 1e-5f;
// ws: pools only, [a*PP + bgc*80 + p], a = 0:mean_h 1:mean_w 2:max_h 3:max_w

__device__ __forceinline__ float sigmoidf(float v) {
    return 1.0f / (1.0f + __expf(-v));
}

// ---------------- K1: per-channel row/col mean+max pools (cold HBM) --------
__global__ __launch_bounds__(256) void k_pool(const float* __restrict__ x,
                                              float* __restrict__ ws) {
    const int bgc = blockIdx.x;                 // 0..4095
    const float* base = x + (size_t)bgc * HW;
    __shared__ float tile[Hh * 84];             // pad stride 84

    for (int v = threadIdx.x; v < 1600; v += 256) {
        int h  = v / 20;
        int w0 = (v % 20) * 4;
        float4 d = ((const float4*)base)[v];
        *(float4*)&tile[h * 84 + w0] = d;
    }
    __syncthreads();

    const int t = threadIdx.x;
    if (t < 80) {
        // row t: mean/max over w  (waves 0-1)
        float s = 0.f, m = -INFINITY;
        const float4* r = (const float4*)&tile[t * 84];
        #pragma unroll
        for (int i = 0; i < 20; i++) {
            float4 d = r[i];
            s += d.x + d.y + d.z + d.w;
            m = fmaxf(m, fmaxf(fmaxf(d.x, d.y), fmaxf(d.z, d.w)));
        }
        ws[0 * PP + bgc * 80 + t] = s * (1.f / 80.f);
        ws[2 * PP + bgc * 80 + t] = m;
    } else if (t >= 128 && t < 208) {
        // col (t-128): mean/max over h  (waves 2-3)
        const int c = t - 128;
        float s2 = 0.f, m2 = -INFINITY;
        #pragma unroll 8
        for (int i = 0; i < 80; i++) {
            float v = tile[i * 84 + c];
            s2 += v;
            m2 = fmaxf(m2, v);
        }
        ws[1 * PP + bgc * 80 + c] = s2 * (1.f / 80.f);
        ws[3 * PP + bgc * 80 + c] = m2;
    }
}

// ---- K2: gates + stats + finalize + output; x re-read from L2/L3 ----------
// 512 blocks x 1024 threads (16 waves): 2 blocks/CU -> up to 32 waves/CU.
// No register cache of x (R6's spill lesson); stats and output each stream
// x from cache (R6 counters: FETCH 59 MB for 2 reads -> L3 absorbs them).
__global__ __launch_bounds__(1024, 4) void k_rest(
    const float* __restrict__ x,
    const float* __restrict__ conv_w,
    const float* __restrict__ conv_b,
    const float* __restrict__ gnw,
    const float* __restrict__ gnb,
    const float* __restrict__ ws,
    float* __restrict__ out)
{
    const int bg  = blockIdx.x;            // 0..511
    const int tid = threadIdx.x;           // 0..1023

    __shared__ float pl[2560];             // pools [a][c][p]
    __shared__ float g[2560];              // gates  [a][c][p]
    __shared__ float wsm[64];
    __shared__ float cbs[8];
    __shared__ float red[16][6];           // per-wave partials (2 waves/ch)
    __shared__ float Axs[8], Bxs[8], Ays[8], Bys[8], ymaxs[8], cHx[8], cHy[8];
    __shared__ float kcs;

    if (tid < 64) wsm[tid] = conv_w[tid];
    if (tid < 8)  cbs[tid] = conv_b[tid];
    #pragma unroll
    for (int i = 0; i < 3; ++i) {
        const int e = tid + i * 1024;
        if (e < 2560) {
            const int a = e / 640, rem = e % 640, c = rem / 80, p = rem % 80;
            pl[e] = ws[a * PP + (bg * 8 + c) * 80 + p];
        }
    }
    __syncthreads();

    // gates = sigmoid(8x8 conv of pools)
    #pragma unroll
    for (int i = 0; i < 3; ++i) {
        const int e = tid + i * 1024;
        if (e < 2560) {
            const int a = e / 640, rem = e % 640, c = rem / 80, p = rem % 80;
            float acc = cbs[c];
            #pragma unroll
            for (int cc = 0; cc < 8; ++cc)
                acc += wsm[c * 8 + cc] * pl[a * 640 + cc * 80 + p];
            g[e] = sigmoidf(acc);
        }
    }
    __syncthreads();

    // ---- stats: 2 waves per channel, stream x from cache ------------------
    const float* base = x + (size_t)bg * CG * HW;
    {
        const int c = tid >> 7, sl = tid & 127;
        const float* cb_ = base + c * HW;
        float s1x = 0.f, s2x = 0.f, s1y = 0.f, s2y = 0.f;
        float my = -INFINITY, ny = INFINITY;
        #pragma unroll 4
        for (int j = 0; j < 13; ++j) {
            const int v = sl + j * 128;
            if (v < 1600) {
                float4 d = ((const float4*)cb_)[v];
                const int h = v / 20, w0 = (v % 20) * 4;
                const float ghx = g[0 * 640 + c * 80 + h];
                const float ghy = g[2 * 640 + c * 80 + h];
                const float4 gwx = *(const float4*)&g[1 * 640 + c * 80 + w0];
                const float4 gwy = *(const float4*)&g[3 * 640 + c * 80 + w0];
                const float dd[4]  = {d.x, d.y, d.z, d.w};
                const float gx4[4] = {gwx.x, gwx.y, gwx.z, gwx.w};
                const float gy4[4] = {gwy.x, gwy.y, gwy.z, gwy.w};
                #pragma unroll
                for (int k = 0; k < 4; ++k) {
                    const float tx = dd[k] * ghx * gx4[k];
                    const float ty = dd[k] * ghy * gy4[k];
                    s1x += tx; s2x += tx * tx;
                    s1y += ty; s2y += ty * ty;
                    my = fmaxf(my, ty); ny = fminf(ny, ty);
                }
            }
        }
        #pragma unroll
        for (int off = 32; off > 0; off >>= 1) {
            s1x += __shfl_down(s1x, off);
            s2x += __shfl_down(s2x, off);
            s1y += __shfl_down(s1y, off);
            s2y += __shfl_down(s2y, off);
            my = fmaxf(my, __shfl_down(my, off));
            ny = fminf(ny, __shfl_down(ny, off));
        }
        const int wv = tid >> 6;
        if ((tid & 63) == 0) {
            red[wv][0] = s1x; red[wv][1] = s2x; red[wv][2] = s1y;
            red[wv][3] = s2y; red[wv][4] = my;  red[wv][5] = ny;
        }
    }
    __syncthreads();

    // ---- finalize affine-norm constants ------------------------------------
    if (tid < 8) {
        const float s1x = red[2 * tid][0] + red[2 * tid + 1][0];
        const float s2x = red[2 * tid][1] + red[2 * tid + 1][1];
        const float s1y = red[2 * tid][2] + red[2 * tid + 1][2];
        const float s2y = red[2 * tid][3] + red[2 * tid + 1][3];
        const float my  = fmaxf(red[2 * tid][4], red[2 * tid + 1][4]);
        const float ny  = fminf(red[2 * tid][5], red[2 * tid + 1][5]);
        const float w = gnw[tid], b = gnb[tid];
        const float mux  = s1x * (1.f / 6400.f);
        const float varx = s2x * (1.f / 6400.f) - mux * mux;
        const float ax   = rsqrtf(varx + EPSf) * w;
        Axs[tid] = ax; Bxs[tid] = b - mux * ax;
        const float muy  = s1y * (1.f / 6400.f);
        const float vary = s2y * (1.f / 6400.f) - muy * muy;
        const float ay   = rsqrtf(vary + EPSf) * w;
        Ays[tid] = ay; Bys[tid] = b - muy * ay;
        ymaxs[tid] = (ay >= 0.f ? my : ny) * ay + Bys[tid];
    }
    __syncthreads();
    if (tid == 0) {
        // x12 = softmax(gn_b): HW-mean of an HW-normalized tensor is gn_b.
        float x12[8], y12[8];
        float mb = -INFINITY;
        for (int c = 0; c < 8; ++c) mb = fmaxf(mb, gnb[c]);
        float se = 0.f;
        for (int c = 0; c < 8; ++c) { x12[c] = __expf(gnb[c] - mb); se += x12[c]; }
        float inv = 1.f / se;
        for (int c = 0; c < 8; ++c) x12[c] *= inv;
        float m2 = -INFINITY;
        for (int c = 0; c < 8; ++c) m2 = fmaxf(m2, ymaxs[c]);
        se = 0.f;
        for (int c = 0; c < 8; ++c) { y12[c] = __expf(ymaxs[c] - m2); se += y12[c]; }
        inv = 1.f / se;
        float kc = 0.f;
        for (int c = 0; c < 8; ++c) {
            y12[c] *= inv;
            cHx[c] = y12[c] * Axs[c];   // scales mean-branch h-gate
            cHy[c] = x12[c] * Ays[c];   // scales max-branch  h-gate
            kc += x12[c] * Bys[c] + y12[c] * Bxs[c];
        }
        kcs = kc;
    }
    __syncthreads();
    if (tid < 640) {
        g[tid]        *= cHx[tid / 80];          // a=0 (mean-branch h)
        g[1280 + tid] *= cHy[tid / 80];          // a=2 (max-branch h)
    }
    __syncthreads();

    // ---- output: weights -> sigmoid -> out (x streamed again) --------------
    const float kc = kcs;
    float* ob = out + (size_t)bg * CG * HW;
    #pragma unroll
    for (int i = 0; i < 2; ++i) {
        const int v = tid + i * 1024;
        if (v < 1600) {
            const int h = v / 20, w0 = (v % 20) * 4;
            float4 gxv[8];
            #pragma unroll
            for (int c = 0; c < 8; ++c)
                gxv[c] = ((const float4*)(base + c * HW))[v];

            float s0 = kc, s1 = kc, s2 = kc, s3 = kc;
            #pragma unroll
            for (int c = 0; c < 8; ++c) {
                const float chx = g[c * 80 + h];
                const float chy = g[1280 + c * 80 + h];
                const float4 cwx = *(const float4*)&g[640  + c * 80 + w0];
                const float4 cwy = *(const float4*)&g[1920 + c * 80 + w0];
                s0 += gxv[c].x * (chy * cwy.x + chx * cwx.x);
                s1 += gxv[c].y * (chy * cwy.y + chx * cwx.y);
                s2 += gxv[c].z * (chy * cwy.z + chx * cwx.z);
                s3 += gxv[c].w * (chy * cwy.w + chx * cwx.w);
            }
            s0 = sigmoidf(s0); s1 = sigmoidf(s1);
            s2 = sigmoidf(s2); s3 = sigmoidf(s3);
            #pragma unroll
            for (int c = 0; c < 8; ++c) {
                float4 o;
                o.x = gxv[c].x * s0; o.y = gxv[c].y * s1;
                o.z = gxv[c].z * s2; o.w = gxv[c].w * s3;
                ((float4*)(ob + c * HW))[v] = o;
            }
        }
    }
}

extern "C" void kernel_launch(void* const* d_in, const int* in_sizes, int n_in,
                              void* d_out, int out_size, void* d_ws, size_t ws_size,
                              hipStream_t stream) {
    const float* x      = (const float*)d_in[0];
    const float* conv_w = (const float*)d_in[1];
    const float* conv_b = (const float*)d_in[2];
    const float* gn_w   = (const float*)d_in[3];
    const float* gn_b   = (const float*)d_in[4];
    float* out = (float*)d_out;
    float* ws  = (float*)d_ws;   // 4*PP floats ~ 5.2 MB

    k_pool<<<NCH, 256, 0, stream>>>(x, ws);
    k_rest<<<NG, 1024, 0, stream>>>(x, conv_w, conv_b, gn_w, gn_b, ws, out);
}